// Round 9
// baseline (291.976 us; speedup 1.0000x reference)
//
#include <hip/hip_runtime.h>
#include <cstddef>

// Problem constants: B=32, N=4096, D=256, K=8 slots, S=16, H=128, 3 iters.
// Strategy (R7/R8 post-mortem): wall = ~205us fixed harness overhead + SUM
// of kernel times; kernel boundaries are ~free, in-kernel cross-block sync
// costs ~12-15us/iteration (measured 3 ways, R1-R7). So: legacy 8-dispatch
// pipeline, each kernel individually optimized. R9: k_proj processes 128
// rows/block (1024 blocks, two 64-row halves reusing the staged weight
// tile) -- halves the 64MB staged-weight re-read and amortizes the serial
// staging preamble. Numerics bit-identical to the verified kernel.

typedef unsigned short ushort_t;
typedef __attribute__((ext_vector_type(8))) short short8;   // 8 bf16 = 4 VGPRs
typedef __attribute__((ext_vector_type(4))) float f32x4;

#define VT_PLANE 2097152   // 32*16*4096 ushorts per plane (hi plane, lo plane)

__device__ __forceinline__ float sigmoid_f(float x){ return 1.f/(1.f+__expf(-x)); }
__device__ __forceinline__ float tanh_f(float x){ return 1.f - 2.f/(__expf(2.f*x)+1.f); }

// fp32 -> bf16 (RNE), as raw bits (weights + mt consistency)
__device__ __forceinline__ ushort_t f2bf(float x){
  unsigned u = __float_as_uint(x);
  return (ushort_t)((u + 0x7FFFu + ((u>>16)&1u)) >> 16);
}
__device__ __forceinline__ float bf2f(ushort_t b){
  return __uint_as_float(((unsigned)b) << 16);
}
// truncation hi/lo split (cheap: AND/SUB/SHR), combined rel err ~2^-17
__device__ __forceinline__ void split_bf(float v, short& hi, short& lo){
  unsigned u = __float_as_uint(v);
  hi = (short)(u >> 16);
  float hf = __uint_as_float(u & 0xFFFF0000u);
  lo = (short)(__float_as_uint(v - hf) >> 16);
}

// ---------------- K0: prep (bf16-split weights, init slots, q1, zeros) -----
__global__ __launch_bounds__(256) void k_prep(
    const float* __restrict__ lnw, const float* __restrict__ lnb,
    const float* __restrict__ wk, const float* __restrict__ wv,
    const float* __restrict__ init_slots,
    const float* __restrict__ ln_s_w, const float* __restrict__ ln_s_b,
    const float* __restrict__ wq,
    ushort_t* __restrict__ Wh, ushort_t* __restrict__ Wl,
    float* __restrict__ mt,
    float* __restrict__ qbuf, float* __restrict__ upd, float* __restrict__ Abuf,
    float* __restrict__ slots_out)
{
  int t = threadIdx.x;
  int i = blockIdx.x*256 + t;          // 32*256 == 8192 exactly
  {
    int s = i >> 8, d = i & 255;
    float w = (s < 16) ? wk[s*256+d] : wv[(s-16)*256+d];
    float w0 = lnw[d]*w;
    ushort_t hb = f2bf(w0);
    ushort_t lb = f2bf(w0 - bf2f(hb));
    Wh[i] = hb; Wl[i] = lb;
  }
  if (blockIdx.x != 0) return;
  // m[s] from QUANTIZED weights; t[s] exact fp32
  {
    int s = t >> 3, j = t & 7;
    float m = 0.f, tv = 0.f;
    for (int d = j; d < 256; d += 8) {
      float w = (s < 16) ? wk[s*256+d] : wv[(s-16)*256+d];
      float w0 = lnw[d]*w;
      ushort_t hb = f2bf(w0);
      float hf = bf2f(hb);
      float lf = bf2f(f2bf(w0 - hf));
      m  += hf + lf;
      tv  = fmaf(lnb[d], w, tv);
    }
    m += __shfl_xor(m,1);  m += __shfl_xor(m,2);  m += __shfl_xor(m,4);
    tv += __shfl_xor(tv,1); tv += __shfl_xor(tv,2); tv += __shfl_xor(tv,4);
    if (j == 0) { mt[s] = m; mt[32+s] = tv; }
  }
  #pragma unroll
  for (int j2 = 0; j2 < 16; ++j2) {
    slots_out[t*16+j2] = init_slots[t*16+j2];
    upd[t*16+j2] = 0.f;
  }
  Abuf[t] = 0.f;
  // q for iteration 1: thread t = (b,k) row
  float sl[16];
  #pragma unroll
  for (int j2 = 0; j2 < 16; ++j2) sl[j2] = init_slots[t*16+j2];
  float mu = 0.f;
  #pragma unroll
  for (int j2 = 0; j2 < 16; ++j2) mu += sl[j2];
  mu *= (1.f/16.f);
  float var = 0.f;
  #pragma unroll
  for (int j2 = 0; j2 < 16; ++j2) { float d = sl[j2]-mu; var = fmaf(d,d,var); }
  var *= (1.f/16.f);
  float rstd = rsqrtf(var + 1e-5f);
  float y[16];
  #pragma unroll
  for (int j2 = 0; j2 < 16; ++j2) y[j2] = (sl[j2]-mu)*rstd*ln_s_w[j2] + ln_s_b[j2];
  #pragma unroll
  for (int tq = 0; tq < 16; ++tq) {
    float q = 0.f;
    #pragma unroll
    for (int s2 = 0; s2 < 16; ++s2) q = fmaf(y[s2], wq[tq*16+s2], q);
    qbuf[t*16+tq] = q;
  }
}

// ---------------- K1: fused LayerNorm + K/V projection ---------------------
// 1024 blocks x 128 rows (two 64-row halves reuse the staged weight tile).
// 4 blocks/CU: 33.8 KB wlds + 4 KB vtile (reused per half) = 37.9 KB.
// v written as TRANSPOSED bf16 hi/lo planes vT[plane][(b*16+s)*4096+n]
// via the vtile LDS bounce; k stays fp32 n-major. Per-row math identical
// to the verified kernel (bit-identical outputs).
__global__ __launch_bounds__(256, 4) void k_proj(
    const float* __restrict__ x, const ushort_t* __restrict__ Wh,
    const ushort_t* __restrict__ Wl, const float* __restrict__ mt,
    float* __restrict__ kout, ushort_t* __restrict__ vT)
{
  __shared__ ushort_t wlds[64*264];   // 33 KB
  __shared__ ushort_t vtile[2*1024];  // 4 KB: [plane][s*64 + lrow], per half
  int t = threadIdx.x;
  int lane = t & 63;
  int p = __builtin_amdgcn_readfirstlane(t >> 6);
  int m = lane & 15, quad = lane >> 4;
  int r0 = blockIdx.x*128;
  {
    const unsigned* srcH = (const unsigned*)Wh;
    const unsigned* srcL = (const unsigned*)Wl;
    unsigned* dst = (unsigned*)wlds;
    #pragma unroll
    for (int i0 = 0; i0 < 8192; i0 += 256) {
      int i = i0 + t;
      int r = i >> 7, w = i & 127;
      unsigned v = (r < 32) ? srcH[r*128 + w] : srcL[(r-32)*128 + w];
      dst[r*132 + w] = v;
    }
  }
  __syncthreads();

  const ushort_t* rhk = wlds + (size_t)m*264 + quad*8;
  const ushort_t* rhv = wlds + (size_t)(16+m)*264 + quad*8;
  const ushort_t* rlk = wlds + (size_t)(32+m)*264 + quad*8;
  const ushort_t* rlv = wlds + (size_t)(48+m)*264 + quad*8;
  float mtk  = mt[m],    mtv  = mt[16+m];
  float mtkb = mt[32+m], mtvb = mt[48+m];

  #pragma unroll 1
  for (int half = 0; half < 2; ++half) {
    int rbase = r0 + half*64;
    const float* xr = x + (size_t)(rbase + p*16 + m)*256 + quad*8;

    f32x4 acck = {0.f,0.f,0.f,0.f}, accv = {0.f,0.f,0.f,0.f};
    float sum = 0.f, sumsq = 0.f;

    #pragma unroll
    for (int kk = 0; kk < 8; ++kk) {
      float4 a0 = *(const float4*)(xr + kk*32);
      float4 a1 = *(const float4*)(xr + kk*32 + 4);
      short8 bh_k = *(const short8*)(rhk + kk*32);
      short8 bh_v = *(const short8*)(rhv + kk*32);
      short8 bl_k = *(const short8*)(rlk + kk*32);
      short8 bl_v = *(const short8*)(rlv + kk*32);
      float xv[8] = {a0.x,a0.y,a0.z,a0.w, a1.x,a1.y,a1.z,a1.w};
      short8 ah, al;
      #pragma unroll
      for (int j = 0; j < 8; ++j) {
        float v = xv[j];
        sum += v; sumsq = fmaf(v, v, sumsq);
        short h_, l_;
        split_bf(v, h_, l_);
        ah[j] = h_; al[j] = l_;
      }
      acck = __builtin_amdgcn_mfma_f32_16x16x32_bf16(ah, bh_k, acck, 0, 0, 0);
      accv = __builtin_amdgcn_mfma_f32_16x16x32_bf16(ah, bh_v, accv, 0, 0, 0);
      acck = __builtin_amdgcn_mfma_f32_16x16x32_bf16(al, bh_k, acck, 0, 0, 0);
      accv = __builtin_amdgcn_mfma_f32_16x16x32_bf16(al, bh_v, accv, 0, 0, 0);
      acck = __builtin_amdgcn_mfma_f32_16x16x32_bf16(ah, bl_k, acck, 0, 0, 0);
      accv = __builtin_amdgcn_mfma_f32_16x16x32_bf16(ah, bl_v, accv, 0, 0, 0);
    }

    sum   += __shfl_xor(sum, 16);  sum   += __shfl_xor(sum, 32);
    sumsq += __shfl_xor(sumsq, 16); sumsq += __shfl_xor(sumsq, 32);

    #pragma unroll
    for (int r = 0; r < 4; ++r) {
      int row = quad*4 + r;                  // C row within the wave tile
      float s_ = __shfl(sum,   row);
      float q_ = __shfl(sumsq, row);
      float mu = s_*(1.f/256.f);
      float var = q_*(1.f/256.f) - mu*mu;
      float rstd = rsqrtf(var + 1e-5f);
      float ok = fmaf(rstd, acck[r] - mu*mtk, mtkb);
      float ov = fmaf(rstd, accv[r] - mu*mtv, mtvb);
      int lrow = p*16 + row;                 // 0..63 within half
      kout[(size_t)(rbase + lrow)*16 + m] = ok;
      short h_, l_;
      split_bf(ov, h_, l_);                  // same fp32 value as before ->
      vtile[m*64 + lrow]        = (ushort_t)h_;   // bit-identical numerics
      vtile[1024 + m*64 + lrow] = (ushort_t)l_;
    }
    __syncthreads();   // vtile complete
    // write vT: 2 planes x 16 s x 64 n ushorts = 4KB; thread t -> 16B
    {
      int plane = t >> 7;        // 0..1
      int idx   = t & 127;       // s = idx>>3, n-seg = (idx&7)*8
      int s = idx >> 3;
      int b = r0 >> 12, nbase = rbase & 4095;
      short8 v8 = *(const short8*)&vtile[plane*1024 + idx*8];
      *(short8*)&vT[(size_t)plane*VT_PLANE + ((size_t)(b*16 + s))*4096
                    + nbase + (idx & 7)*8] = v8;
    }
    __syncthreads();   // vtile free for next half
  }
}

// ---------------- K2: logits + softmax-over-slots + MFMA update ------------
// V path removed entirely: wave0 loads PV B-fragments straight from the
// L3-hot vT planes. LDS = pt(8.4K)+qs+apart ~9KB -> high occupancy.
__global__ __launch_bounds__(256) void k_attn(
    const float* __restrict__ kproj, const ushort_t* __restrict__ vT,
    const float* __restrict__ qbuf,
    float* __restrict__ upd, float* __restrict__ Abuf,
    float* __restrict__ attn_out, int write_attn)
{
  __shared__ ushort_t pt[16*264];   // rows 0..7 = p_hi[kk][n], 8..15 = p_lo
  __shared__ float qs[128];
  __shared__ float apart[4][8];
  int b = blockIdx.x >> 4;
  int n0 = (blockIdx.x & 15) * 256;
  int t = threadIdx.x;
  int w = t >> 6, lane = t & 63;

  if (t < 128) qs[t] = qbuf[b*128 + t];

  const float* kr = kproj + ((size_t)(b*4096 + n0 + t))*16;
  float kv[16];
  #pragma unroll
  for (int j = 0; j < 16; j += 4) {
    float4 f = *(const float4*)(kr+j);
    kv[j]=f.x; kv[j+1]=f.y; kv[j+2]=f.z; kv[j+3]=f.w;
  }
  __syncthreads();   // qs ready

  float p8[8];
  {
    float lg[8];
    #pragma unroll
    for (int kk = 0; kk < 8; ++kk) {
      float a = 0.f;
      #pragma unroll
      for (int s = 0; s < 16; ++s) a = fmaf(qs[kk*16+s], kv[s], a);
      lg[kk] = a*0.25f;  // scale = 16^-0.5
    }
    float mx = lg[0];
    #pragma unroll
    for (int kk = 1; kk < 8; ++kk) mx = fmaxf(mx, lg[kk]);
    float se = 0.f;
    #pragma unroll
    for (int kk = 0; kk < 8; ++kk) { lg[kk] = __expf(lg[kk]-mx); se += lg[kk]; }
    float inv = 1.f/se;
    #pragma unroll
    for (int kk = 0; kk < 8; ++kk) {
      float pv = fmaf(lg[kk], inv, 1e-8f);   // softmax + EPS (pre-renorm)
      p8[kk] = pv;
      if (write_attn) attn_out[((size_t)(b*8+kk))*4096 + n0 + t] = pv;
    }
  }
  #pragma unroll
  for (int kk = 0; kk < 8; ++kk) {
    float r = p8[kk];
    r += __shfl_xor(r, 1);  r += __shfl_xor(r, 2);  r += __shfl_xor(r, 4);
    r += __shfl_xor(r, 8);  r += __shfl_xor(r, 16); r += __shfl_xor(r, 32);
    if (lane == 0) apart[w][kk] = r;
  }
  #pragma unroll
  for (int kk = 0; kk < 8; ++kk) {
    short h_, l_;
    split_bf(p8[kk], h_, l_);
    pt[kk*264 + t]     = (ushort_t)h_;
    pt[(8+kk)*264 + t] = (ushort_t)l_;
  }
  __syncthreads();

  if (t < 8)
    atomicAdd(Abuf + b*8 + t,
              apart[0][t] + apart[1][t] + apart[2][t] + apart[3][t]);

  if (w == 0) {   // wave 0: updates = P . V via MFMA; V fragments from vT
    int mm = lane & 15, quad = lane >> 4;
    const short8 z8 = {0,0,0,0,0,0,0,0};
    const ushort_t* vhi = vT + ((size_t)(b*16 + mm))*4096 + n0;
    const ushort_t* vlo = vhi + (size_t)VT_PLANE;
    f32x4 acc = {0.f,0.f,0.f,0.f};
    #pragma unroll
    for (int c = 0; c < 8; ++c) {
      int k0 = c*32 + quad*8;
      short8 ah = (mm < 8) ? *(const short8*)&pt[mm*264 + k0]     : z8;
      short8 al = (mm < 8) ? *(const short8*)&pt[(8+mm)*264 + k0] : z8;
      short8 bh = *(const short8*)(vhi + k0);
      short8 bl = *(const short8*)(vlo + k0);
      acc = __builtin_amdgcn_mfma_f32_16x16x32_bf16(ah, bh, acc, 0, 0, 0);
      acc = __builtin_amdgcn_mfma_f32_16x16x32_bf16(al, bh, acc, 0, 0, 0);
      acc = __builtin_amdgcn_mfma_f32_16x16x32_bf16(ah, bl, acc, 0, 0, 0);
    }
    int s = lane & 15;
    #pragma unroll
    for (int r = 0; r < 4; ++r) {
      int kk = quad*4 + r;
      if (kk < 8) atomicAdd(upd + (b*8+kk)*16 + s, acc[r]);
    }
  }
}

// -------- GRU cell + LN + MLP body (shared by k_gru and k_final) -----------
__device__ __forceinline__ void gru_body(
    int bk, int s, int laneBase, int prep_next,
    float* upd, float* Abuf, float* slots, float* qbuf,
    const float* s_wih, const float* s_whh,
    const float* s_bih, const float* s_bhh,
    const float* s_w1, const float* s_b1,
    const float* s_w2, const float* s_b2,
    const float* s_lnmw, const float* s_lnmb,
    const float* s_lnsw, const float* s_lnsb, const float* s_wq)
{
  float inv = 1.f / Abuf[bk];
  float u[16], h[16];
  #pragma unroll
  for (int j = 0; j < 16; ++j) {
    u[j] = upd[bk*16+j] * inv;
    h[j] = slots[bk*16+j];
  }
  float hs = slots[bk*16+s];

  float gir = s_bih[s],  giz = s_bih[16+s], gin = s_bih[32+s];
  float ghr = s_bhh[s],  ghz = s_bhh[16+s], ghn = s_bhh[32+s];
  #pragma unroll
  for (int j = 0; j < 16; ++j) {
    gir = fmaf(u[j], s_wih[s*17+j], gir);
    giz = fmaf(u[j], s_wih[(16+s)*17+j], giz);
    gin = fmaf(u[j], s_wih[(32+s)*17+j], gin);
    ghr = fmaf(h[j], s_whh[s*17+j], ghr);
    ghz = fmaf(h[j], s_whh[(16+s)*17+j], ghz);
    ghn = fmaf(h[j], s_whh[(32+s)*17+j], ghn);
  }
  float rr = sigmoid_f(gir + ghr);
  float zz = sigmoid_f(giz + ghz);
  float nn = tanh_f(gin + rr*ghn);
  float hn = (1.f-zz)*nn + zz*hs;

  float ssum = hn;
  #pragma unroll
  for (int mm = 1; mm < 16; mm <<= 1) ssum += __shfl_xor(ssum, mm);
  float mu = ssum*(1.f/16.f);
  float dv = hn - mu;
  float vs = dv*dv;
  #pragma unroll
  for (int mm = 1; mm < 16; mm <<= 1) vs += __shfl_xor(vs, mm);
  float rstd = rsqrtf(vs*(1.f/16.f) + 1e-5f);
  float y = dv*rstd*s_lnmw[s] + s_lnmb[s];

  float yv[16];
  #pragma unroll
  for (int j = 0; j < 16; ++j) yv[j] = __shfl(y, laneBase + j);

  float h1[8];
  #pragma unroll
  for (int i = 0; i < 8; ++i) {
    int jj = i*16 + s;
    float a = s_b1[jj];
    #pragma unroll
    for (int q = 0; q < 16; ++q) a = fmaf(yv[q], s_w1[jj*17+q], a);
    h1[i] = fmaxf(a, 0.f);
  }
  float o = s_b2[s];
  #pragma unroll
  for (int i = 0; i < 8; ++i) {
    #pragma unroll
    for (int sp = 0; sp < 16; ++sp) {
      float hv = __shfl(h1[i], laneBase + sp);
      o = fmaf(hv, s_w2[s*129 + i*16 + sp], o);
    }
  }
  float slot_new = hn + o;
  slots[bk*16+s] = slot_new;

  if (prep_next) {
    float ss = slot_new;
    #pragma unroll
    for (int mm = 1; mm < 16; mm <<= 1) ss += __shfl_xor(ss, mm);
    float mu2 = ss*(1.f/16.f);
    float d2 = slot_new - mu2;
    float v2 = d2*d2;
    #pragma unroll
    for (int mm = 1; mm < 16; mm <<= 1) v2 += __shfl_xor(v2, mm);
    float rstd2 = rsqrtf(v2*(1.f/16.f) + 1e-5f);
    float y2 = d2*rstd2*s_lnsw[s] + s_lnsb[s];
    float qv = 0.f;
    #pragma unroll
    for (int sp = 0; sp < 16; ++sp)
      qv = fmaf(__shfl(y2, laneBase+sp), s_wq[s*17+sp], qv);
    qbuf[bk*16+s] = qv;
    upd[bk*16+s] = 0.f;
    if (s == 0) Abuf[bk] = 0.f;
  }
}

#define GRU_STAGE_LDS()                                                      \
  __shared__ float s_wih[48*17], s_whh[48*17];                               \
  __shared__ float s_bih[48], s_bhh[48];                                     \
  __shared__ float s_w1[128*17], s_b1[128];                                  \
  __shared__ float s_w2[16*129], s_b2[16];                                   \
  __shared__ float s_lnmw[16], s_lnmb[16], s_lnsw[16], s_lnsb[16];           \
  __shared__ float s_wq[16*17];                                              \
  {                                                                          \
    int t_ = threadIdx.x;                                                    \
    for (int i = t_; i < 768; i += 256) {                                    \
      int g = i >> 4, j = i & 15;                                            \
      s_wih[g*17+j] = w_ih[i];                                               \
      s_whh[g*17+j] = w_hh[i];                                               \
    }                                                                        \
    for (int i = t_; i < 2048; i += 256) {                                   \
      int r = i >> 4, c = i & 15;                                            \
      s_w1[r*17+c] = mlp_w1[i];                                              \
      int r2 = i >> 7, c2 = i & 127;                                         \
      s_w2[r2*129+c2] = mlp_w2[i];                                           \
    }                                                                        \
    if (t_ < 48) { s_bih[t_] = b_ih[t_]; s_bhh[t_] = b_hh[t_]; }             \
    if (t_ < 128) s_b1[t_] = mlp_b1[t_];                                     \
    if (t_ < 16) {                                                           \
      s_b2[t_] = mlp_b2[t_];                                                 \
      s_lnmw[t_] = ln_m_w[t_]; s_lnmb[t_] = ln_m_b[t_];                      \
      s_lnsw[t_] = ln_s_w[t_]; s_lnsb[t_] = ln_s_b[t_];                      \
    }                                                                        \
    for (int i = t_; i < 256; i += 256) {                                    \
      int r = i >> 4, c = i & 15;                                            \
      s_wq[r*17+c] = wq[i];                                                  \
    }                                                                        \
  }                                                                          \
  __syncthreads();

// ---------------- K3: GRU for iterations 0,1 (16 blocks) -------------------
__global__ __launch_bounds__(256) void k_gru(
    float* __restrict__ upd, float* __restrict__ Abuf,
    float* __restrict__ slots, float* __restrict__ qbuf,
    const float* __restrict__ w_ih, const float* __restrict__ w_hh,
    const float* __restrict__ b_ih, const float* __restrict__ b_hh,
    const float* __restrict__ mlp_w1, const float* __restrict__ mlp_b1,
    const float* __restrict__ mlp_w2, const float* __restrict__ mlp_b2,
    const float* __restrict__ ln_m_w, const float* __restrict__ ln_m_b,
    const float* __restrict__ ln_s_w, const float* __restrict__ ln_s_b,
    const float* __restrict__ wq)
{
  GRU_STAGE_LDS()
  int t = threadIdx.x;
  int bk = blockIdx.x*16 + (t >> 4);
  int s = t & 15;
  int laneBase = (t & 63) & ~15;
  gru_body(bk, s, laneBase, 1, upd, Abuf, slots, qbuf,
           s_wih, s_whh, s_bih, s_bhh, s_w1, s_b1, s_w2, s_b2,
           s_lnmw, s_lnmb, s_lnsw, s_lnsb, s_wq);
}

// ---------------- K4: final GRU (it 2) + attn normalization (fused) --------
__global__ __launch_bounds__(256) void k_final(
    float* __restrict__ upd, float* __restrict__ Abuf,
    float* __restrict__ slots, float* __restrict__ qbuf,
    float* __restrict__ attn,
    const float* __restrict__ w_ih, const float* __restrict__ w_hh,
    const float* __restrict__ b_ih, const float* __restrict__ b_hh,
    const float* __restrict__ mlp_w1, const float* __restrict__ mlp_b1,
    const float* __restrict__ mlp_w2, const float* __restrict__ mlp_b2,
    const float* __restrict__ ln_m_w, const float* __restrict__ ln_m_b,
    const float* __restrict__ ln_s_w, const float* __restrict__ ln_s_b,
    const float* __restrict__ wq)
{
  int t = threadIdx.x;
  {
    int bk = blockIdx.x;
    float inv = 1.f / Abuf[bk];
    float4* p = (float4*)(attn + (size_t)bk*4096);
    #pragma unroll 4
    for (int i = t; i < 1024; i += 256) {
      float4 v = p[i];
      v.x *= inv; v.y *= inv; v.z *= inv; v.w *= inv;
      p[i] = v;
    }
  }
  if (blockIdx.x >= 16) return;
  GRU_STAGE_LDS()
  int bk = blockIdx.x*16 + (t >> 4);
  int s = t & 15;
  int laneBase = (t & 63) & ~15;
  gru_body(bk, s, laneBase, 0, upd, Abuf, slots, qbuf,
           s_wih, s_whh, s_bih, s_bhh, s_w1, s_b1, s_w2, s_b2,
           s_lnmw, s_lnmb, s_lnsw, s_lnsb, s_wq);
}

extern "C" void kernel_launch(void* const* d_in, const int* in_sizes, int n_in,
                              void* d_out, int out_size, void* d_ws, size_t ws_size,
                              hipStream_t stream)
{
  const float* inputs     = (const float*)d_in[0];
  const float* init_slots = (const float*)d_in[1];
  const float* ln_in_w    = (const float*)d_in[2];
  const float* ln_in_b    = (const float*)d_in[3];
  const float* ln_s_w     = (const float*)d_in[4];
  const float* ln_s_b     = (const float*)d_in[5];
  const float* ln_m_w     = (const float*)d_in[6];
  const float* ln_m_b     = (const float*)d_in[7];
  const float* wq         = (const float*)d_in[8];
  const float* wk         = (const float*)d_in[9];
  const float* wv         = (const float*)d_in[10];
  const float* w_ih       = (const float*)d_in[11];
  const float* w_hh       = (const float*)d_in[12];
  const float* b_ih       = (const float*)d_in[13];
  const float* b_hh       = (const float*)d_in[14];
  const float* mlp_w1     = (const float*)d_in[15];
  const float* mlp_b1     = (const float*)d_in[16];
  const float* mlp_w2     = (const float*)d_in[17];
  const float* mlp_b2     = (const float*)d_in[18];

  float* ws    = (float*)d_ws;
  ushort_t* Wh = (ushort_t*)ws;            // 8192 ushorts (16 KB)
  ushort_t* Wl = (ushort_t*)(ws + 4096);   // 8192 ushorts (16 KB)
  float* mt    = ws + 8192;          // 64
  float* qbuf  = ws + 8320;          // 4096
  float* upd   = ws + 12416;         // 4096
  float* Abuf  = ws + 16512;         // 256
  float* kproj = ws + 16768;         // 2097152 floats (8 MB)
  ushort_t* vT = (ushort_t*)(ws + 16768 + 2097152);  // 2 planes x 2M ushorts

  float* out   = (float*)d_out;
  float* slots = out;                // [32,8,16]
  float* attn  = out + 4096;         // [32,8,4096]

  k_prep<<<32, 256, 0, stream>>>(ln_in_w, ln_in_b, wk, wv, init_slots,
                                 ln_s_w, ln_s_b, wq,
                                 Wh, Wl, mt, qbuf, upd, Abuf, slots);
  k_proj<<<1024, 256, 0, stream>>>(inputs, Wh, Wl, mt, kproj, vT);
  for (int it = 0; it < 3; ++it) {
    int last = (it == 2);
    k_attn<<<512, 256, 0, stream>>>(kproj, vT, qbuf, upd, Abuf, attn, last);
    if (!last)
      k_gru<<<16, 256, 0, stream>>>(upd, Abuf, slots, qbuf,
                                    w_ih, w_hh, b_ih, b_hh,
                                    mlp_w1, mlp_b1, mlp_w2, mlp_b2,
                                    ln_m_w, ln_m_b, ln_s_w, ln_s_b, wq);
  }
  k_final<<<256, 256, 0, stream>>>(upd, Abuf, slots, qbuf, attn,
                                   w_ih, w_hh, b_ih, b_hh,
                                   mlp_w1, mlp_b1, mlp_w2, mlp_b2,
                                   ln_m_w, ln_m_b, ln_s_w, ln_s_b, wq);
}